// Round 1
// baseline (1397.282 us; speedup 1.0000x reference)
//
#include <hip/hip_runtime.h>
#include <cstdint>

#define THR 1e-6f
#define N_ROWS 16384
#define CIN 4096
#define COUT 4096
#define TILES 256   // N_ROWS / 64
#define KCAP 2048   // padded per-tile active-channel capacity (data max ~1750)

typedef _Float16 f16x8 __attribute__((ext_vector_type(8)));
typedef float floatx4 __attribute__((ext_vector_type(4)));

static __device__ __forceinline__ unsigned short f16b(_Float16 h) {
  union { _Float16 f; unsigned short u; } c; c.f = h; return c.u;
}

static __device__ __forceinline__ void gl_lds16(const void* g, void* l) {
  __builtin_amdgcn_global_load_lds(
      (const __attribute__((address_space(1))) void*)g,
      (__attribute__((address_space(3))) void*)l, 16, 0, 0);
}

// ---------------------------------------------------------------------------
// Kernel 1: W[o][c] fp32  ->  Wtp[c][o] u32 = (fp16_hi << 16) | fp16_lo
// 64x64 LDS tile transpose, coalesced both sides.
// ---------------------------------------------------------------------------
__global__ __launch_bounds__(256) void k_wsplit(const float* __restrict__ W,
                                                uint32_t* __restrict__ Wtp) {
  __shared__ float t[64][65];
  int c0 = (blockIdx.x & 63) << 6;
  int o0 = (blockIdx.x >> 6) << 6;
  int tid = threadIdx.x;
#pragma unroll
  for (int q = 0; q < 16; ++q) {
    int idx = q * 256 + tid;
    int ro = idx >> 6, ci = idx & 63;
    t[ci][ro] = W[(size_t)(o0 + ro) * CIN + c0 + ci];
  }
  __syncthreads();
#pragma unroll
  for (int q = 0; q < 16; ++q) {
    int idx = q * 256 + tid;
    int cr = idx >> 6, oi = idx & 63;
    float v = t[cr][oi];
    _Float16 h = (_Float16)v;
    _Float16 l = (_Float16)(v - (float)h);
    Wtp[(size_t)(c0 + cr) * COUT + o0 + oi] = ((uint32_t)f16b(h) << 16) | f16b(l);
  }
}

// ---------------------------------------------------------------------------
// Kernel 2: per tile t: col-max over 64 rows -> active list (prefix scan),
// pad count to x64, write gidx (ushort) + compacted xh/xl fp16 planes [b][k].
// ---------------------------------------------------------------------------
__global__ __launch_bounds__(256) void k_prescan(const float* __restrict__ x,
                                                 unsigned short* __restrict__ gidx,
                                                 int* __restrict__ cnts,
                                                 unsigned short* __restrict__ xch,
                                                 unsigned short* __restrict__ xcl) {
  int t = blockIdx.x;
  int tid = threadIdx.x;
  const float* xt = x + (size_t)t * 64 * CIN;

  float mx[16];
#pragma unroll
  for (int i = 0; i < 16; ++i) mx[i] = 0.f;
  for (int b = 0; b < 64; ++b) {
    const float4* row4 = (const float4*)(xt + (size_t)b * CIN);
#pragma unroll
    for (int j = 0; j < 4; ++j) {
      float4 v = row4[tid * 4 + j];
      mx[j * 4 + 0] = fmaxf(mx[j * 4 + 0], fabsf(v.x));
      mx[j * 4 + 1] = fmaxf(mx[j * 4 + 1], fabsf(v.y));
      mx[j * 4 + 2] = fmaxf(mx[j * 4 + 2], fabsf(v.z));
      mx[j * 4 + 3] = fmaxf(mx[j * 4 + 3], fabsf(v.w));
    }
  }
  int cnt = 0;
#pragma unroll
  for (int i = 0; i < 16; ++i) cnt += (mx[i] > THR) ? 1 : 0;

  __shared__ int scan[256];
  __shared__ unsigned short sidx[KCAP];
  scan[tid] = cnt;
  __syncthreads();
  for (int s = 1; s < 256; s <<= 1) {
    int v = (tid >= s) ? scan[tid - s] : 0;
    __syncthreads();
    scan[tid] += v;
    __syncthreads();
  }
  int pos = scan[tid] - cnt;           // exclusive prefix
  int total = scan[255];
  int cntPad = (total + 63) & ~63;
  if (cntPad > KCAP) cntPad = KCAP;

#pragma unroll
  for (int i = 0; i < 16; ++i) {
    if (mx[i] > THR) {
      if (pos < KCAP) sidx[pos] = (unsigned short)(tid * 16 + i);
      ++pos;
    }
  }
  for (int k = total + tid; k < cntPad; k += 256) sidx[k] = 0;
  if (tid == 0) cnts[t] = cntPad;
  __syncthreads();

  for (int k = tid; k < cntPad; k += 256) gidx[t * KCAP + k] = sidx[k];

  for (int b = 0; b < 64; ++b) {
    const float* row = xt + (size_t)b * CIN;
    size_t obase = ((size_t)t * 64 + b) * KCAP;
    for (int k = tid; k < cntPad; k += 256) {
      float v = (k < total) ? row[sidx[k]] : 0.f;
      _Float16 h = (_Float16)v;
      _Float16 l = (_Float16)(v - (float)h);
      xch[obase + k] = f16b(h);
      xcl[obase + k] = f16b(l);
    }
  }
}

// ---------------------------------------------------------------------------
// Kernel 3: sparse GEMM. Block = 64 rows x 256 cols, 4 waves (each 64x64).
// A (compacted x fp16 hi/lo) via global_load_lds -> XOR-swizzled LDS.
// B (Wtp rows, gathered by channel idx) direct global->VGPR, packed u32.
// 3-term fp16 MFMA: Ah*Bh + Al*Bh + Ah*Bl.
// ---------------------------------------------------------------------------
__global__ __launch_bounds__(256, 2) void k_gemm(const uint32_t* __restrict__ Wtp,
                                                 const unsigned short* __restrict__ gidx,
                                                 const int* __restrict__ cnts,
                                                 const unsigned short* __restrict__ xch,
                                                 const unsigned short* __restrict__ xcl,
                                                 const float* __restrict__ bias,
                                                 float* __restrict__ out) {
  __shared__ __attribute__((aligned(16))) char sA[16384];  // [0,8K) hi, [8K,16K) lo

  // XCD-aware remap: each XCD works one 256-col Wtp stripe (4MB, L2-resident)
  int bid = blockIdx.x + gridDim.x * blockIdx.y;
  int xcd = bid & 7;
  int i = bid >> 3;            // 0..511
  int t = i & 255;
  int o0 = ((xcd << 1) + (i >> 8)) << 8;

  int tid = threadIdx.x;
  int lane = tid & 63;
  int w = tid >> 6;
  int l15 = lane & 15, g = lane >> 4;
  int cntPad = cnts[t];

  floatx4 acc[4][4];
#pragma unroll
  for (int m = 0; m < 4; ++m)
#pragma unroll
    for (int n = 0; n < 4; ++n) acc[m][n] = (floatx4)0.f;

  // staging source pre-unswizzle (content lands XOR-swizzled in LDS)
  int jx = ((lane & 7) * 16) ^ (((lane >> 3) & 7) << 4);
  int brow_s = lane >> 3;  // row within an 8-row chunk

  const int tKC = t * KCAP;

  for (int k0 = 0; k0 < cntPad; k0 += 64) {
    // prefetch channel indices for this K-step (no LDS dependence)
    int cI[2][8];
#pragma unroll
    for (int ks = 0; ks < 2; ++ks)
#pragma unroll
      for (int q = 0; q < 8; ++q)
        cI[ks][q] = gidx[tKC + k0 + ks * 32 + g * 8 + q];

    __syncthreads();  // all waves done reading sA from previous step
#pragma unroll
    for (int q = 0; q < 4; ++q) {
      int ch = w + 4 * q;              // 16 1KB chunks over 2 planes
      int plane = ch >> 3;
      int coff = (ch & 7) * 1024;
      int b = ((ch & 7) << 3) + brow_s;
      const unsigned short* srcp = plane ? xcl : xch;
      const char* gsrc = (const char*)(srcp + ((size_t)(t * 64 + b) * KCAP + k0)) + jx;
      gl_lds16(gsrc, sA + plane * 8192 + coff);
    }
    __syncthreads();  // drains vmcnt -> A staged

#pragma unroll
    for (int ks = 0; ks < 2; ++ks) {
      f16x8 Ah[4], Al[4];
#pragma unroll
      for (int m = 0; m < 4; ++m) {
        int b = m * 16 + l15;
        int off = (b * 128 + ks * 64 + g * 16) ^ ((b & 7) << 4);
        Ah[m] = *(const f16x8*)(sA + off);
        Al[m] = *(const f16x8*)(sA + 8192 + off);
      }
#pragma unroll
      for (int n = 0; n < 4; ++n) {
        int ocol = o0 + w * 64 + n * 16 + l15;
        uint32_t wv[8];
#pragma unroll
        for (int q = 0; q < 8; ++q)
          wv[q] = Wtp[(size_t)cI[ks][q] * COUT + ocol];
        union { f16x8 v; uint32_t u[4]; } Bh, Bl;
#pragma unroll
        for (int j = 0; j < 4; ++j) {
          Bh.u[j] = (wv[2 * j] >> 16) | (wv[2 * j + 1] & 0xFFFF0000u);
          Bl.u[j] = (wv[2 * j] & 0xFFFFu) | (wv[2 * j + 1] << 16);
        }
#pragma unroll
        for (int m = 0; m < 4; ++m) {
          acc[m][n] = __builtin_amdgcn_mfma_f32_16x16x32_f16(Ah[m], Bh.v, acc[m][n], 0, 0, 0);
          acc[m][n] = __builtin_amdgcn_mfma_f32_16x16x32_f16(Al[m], Bh.v, acc[m][n], 0, 0, 0);
          acc[m][n] = __builtin_amdgcn_mfma_f32_16x16x32_f16(Ah[m], Bl.v, acc[m][n], 0, 0, 0);
        }
      }
    }
  }

  // epilogue: D row = (lane>>4)*4 + r, col = lane&15 (m89-verified mapping)
#pragma unroll
  for (int n = 0; n < 4; ++n) {
    int ocol = o0 + w * 64 + n * 16 + l15;
    float bv = bias[ocol];
#pragma unroll
    for (int m = 0; m < 4; ++m) {
      int row0 = t * 64 + m * 16 + g * 4;
#pragma unroll
      for (int r = 0; r < 4; ++r)
        out[(size_t)(row0 + r) * COUT + ocol] = acc[m][n][r] + bv;
    }
  }
}

// ---------------------------------------------------------------------------
// Fallback: plain dense fp32 tiled GEMM (only if ws_size too small).
// Valid because inactive channels are exactly zero in x.
// ---------------------------------------------------------------------------
__global__ __launch_bounds__(256) void k_dense_fallback(const float* __restrict__ x,
                                                        const float* __restrict__ W,
                                                        const float* __restrict__ bias,
                                                        float* __restrict__ out) {
  __shared__ float As[64][17];
  __shared__ float Bs[16][65];
  int r0 = blockIdx.y << 6, c0 = blockIdx.x << 6;
  int tid = threadIdx.x;
  int ty = tid >> 4, tx = tid & 15;
  float acc[4][4] = {};
  for (int k0 = 0; k0 < CIN; k0 += 16) {
    __syncthreads();
    {
      int bb = tid >> 2, kk = (tid & 3) * 4;
      float4 va = *(const float4*)&x[(size_t)(r0 + bb) * CIN + k0 + kk];
      As[bb][kk] = va.x; As[bb][kk + 1] = va.y; As[bb][kk + 2] = va.z; As[bb][kk + 3] = va.w;
      float4 vb = *(const float4*)&W[(size_t)(c0 + bb) * CIN + k0 + kk];
      Bs[kk][bb] = vb.x; Bs[kk + 1][bb] = vb.y; Bs[kk + 2][bb] = vb.z; Bs[kk + 3][bb] = vb.w;
    }
    __syncthreads();
#pragma unroll
    for (int kk = 0; kk < 16; ++kk) {
      float a[4], b[4];
#pragma unroll
      for (int q = 0; q < 4; ++q) a[q] = As[ty * 4 + q][kk];
#pragma unroll
      for (int j = 0; j < 4; ++j) b[j] = Bs[kk][tx * 4 + j];
#pragma unroll
      for (int q = 0; q < 4; ++q)
#pragma unroll
        for (int j = 0; j < 4; ++j) acc[q][j] += a[q] * b[j];
    }
  }
#pragma unroll
  for (int q = 0; q < 4; ++q) {
    int row = r0 + ty * 4 + q;
#pragma unroll
    for (int j = 0; j < 4; ++j) {
      int col = c0 + tx * 4 + j;
      out[(size_t)row * COUT + col] = acc[q][j] + bias[col];
    }
  }
}

extern "C" void kernel_launch(void* const* d_in, const int* in_sizes, int n_in,
                              void* d_out, int out_size, void* d_ws, size_t ws_size,
                              hipStream_t stream) {
  (void)in_sizes; (void)n_in; (void)out_size;
  const float* x = (const float*)d_in[0];
  const float* W = (const float*)d_in[1];
  const float* bias = (const float*)d_in[2];
  float* out = (float*)d_out;

  size_t offWtp = 0;
  size_t offXch = offWtp + (size_t)CIN * COUT * 4;      // 64 MB
  size_t offXcl = offXch + (size_t)N_ROWS * KCAP * 2;   // +64 MB
  size_t offIdx = offXcl + (size_t)N_ROWS * KCAP * 2;   // +64 MB
  size_t offCnt = offIdx + (size_t)TILES * KCAP * 2;    // +1 MB
  size_t need = offCnt + (size_t)TILES * 4;

  if (ws_size < need) {
    dim3 g(COUT / 64, N_ROWS / 64);
    k_dense_fallback<<<g, 256, 0, stream>>>(x, W, bias, out);
    return;
  }

  char* ws = (char*)d_ws;
  uint32_t* Wtp = (uint32_t*)(ws + offWtp);
  unsigned short* xch = (unsigned short*)(ws + offXch);
  unsigned short* xcl = (unsigned short*)(ws + offXcl);
  unsigned short* gidx = (unsigned short*)(ws + offIdx);
  int* cnts = (int*)(ws + offCnt);

  k_wsplit<<<dim3(64 * 64), 256, 0, stream>>>(W, Wtp);
  k_prescan<<<dim3(TILES), 256, 0, stream>>>(x, gidx, cnts, xch, xcl);
  k_gemm<<<dim3(COUT / 256, TILES), 256, 0, stream>>>(Wtp, gidx, cnts, xch, xcl, bias, out);
}

// Round 4
// 1285.937 us; speedup vs baseline: 1.0866x; 1.0866x over previous
//
#include <hip/hip_runtime.h>
#include <cstdint>

#define THR 1e-6f
#define N_ROWS 16384
#define CIN 4096
#define COUT 4096
#define TILES 256   // N_ROWS / 64
#define KCAP 2048   // padded per-tile active-channel capacity (data max ~1750)

typedef _Float16 f16x8 __attribute__((ext_vector_type(8)));
typedef float floatx4 __attribute__((ext_vector_type(4)));

static __device__ __forceinline__ unsigned short f16b(_Float16 h) {
  union { _Float16 f; unsigned short u; } c; c.f = h; return c.u;
}

static __device__ __forceinline__ void gl_lds16(const void* g, void* l) {
  __builtin_amdgcn_global_load_lds(
      (const __attribute__((address_space(1))) void*)g,
      (__attribute__((address_space(3))) void*)l, 16, 0, 0);
}

// ---------------------------------------------------------------------------
// Kernel 1: W[o][c] fp32  ->  Wtp[c][o] u32 = (fp16_hi << 16) | fp16_lo
// ---------------------------------------------------------------------------
__global__ __launch_bounds__(256) void k_wsplit(const float* __restrict__ W,
                                                uint32_t* __restrict__ Wtp) {
  __shared__ float t[64][65];
  int c0 = (blockIdx.x & 63) << 6;
  int o0 = (blockIdx.x >> 6) << 6;
  int tid = threadIdx.x;
#pragma unroll
  for (int q = 0; q < 16; ++q) {
    int idx = q * 256 + tid;
    int ro = idx >> 6, ci = idx & 63;
    t[ci][ro] = W[(size_t)(o0 + ro) * CIN + c0 + ci];
  }
  __syncthreads();
#pragma unroll
  for (int q = 0; q < 16; ++q) {
    int idx = q * 256 + tid;
    int cr = idx >> 6, oi = idx & 63;
    float v = t[cr][oi];
    _Float16 h = (_Float16)v;
    _Float16 l = (_Float16)(v - (float)h);
    Wtp[(size_t)(c0 + cr) * COUT + o0 + oi] = ((uint32_t)f16b(h) << 16) | f16b(l);
  }
}

// ---------------------------------------------------------------------------
// P1: per (tile, channel) activity flag. 1024 blocks, fully coalesced.
// ---------------------------------------------------------------------------
__global__ __launch_bounds__(256) void k_colmax(const float* __restrict__ x,
                                                unsigned char* __restrict__ flags) {
  int t = blockIdx.x >> 2;
  int q = blockIdx.x & 3;
  int c = (q << 10) + threadIdx.x * 4;
  const float* xt = x + (size_t)t * 64 * CIN;
  float4 m = {0.f, 0.f, 0.f, 0.f};
  for (int b = 0; b < 64; ++b) {
    float4 v = *(const float4*)(xt + (size_t)b * CIN + c);
    m.x = fmaxf(m.x, fabsf(v.x));
    m.y = fmaxf(m.y, fabsf(v.y));
    m.z = fmaxf(m.z, fabsf(v.z));
    m.w = fmaxf(m.w, fabsf(v.w));
  }
  uchar4 fl;
  fl.x = m.x > THR; fl.y = m.y > THR; fl.z = m.z > THR; fl.w = m.w > THR;
  *(uchar4*)&flags[(size_t)t * CIN + c] = fl;
}

// ---------------------------------------------------------------------------
// P2: per-tile prefix scan of flags -> gidx list (padded), ppos map, counts.
// ---------------------------------------------------------------------------
__global__ __launch_bounds__(256) void k_scan(const unsigned char* __restrict__ flags,
                                              unsigned short* __restrict__ gidx,
                                              int* __restrict__ cnts,
                                              int* __restrict__ tots,
                                              unsigned short* __restrict__ ppos) {
  int t = blockIdx.x, tid = threadIdx.x;
  const unsigned char* f = flags + (size_t)t * CIN;
  uint4 v = *(const uint4*)(f + tid * 16);
  int cnt = (int)((v.x * 0x01010101u) >> 24) + (int)((v.y * 0x01010101u) >> 24) +
            (int)((v.z * 0x01010101u) >> 24) + (int)((v.w * 0x01010101u) >> 24);
  __shared__ int scan[256];
  scan[tid] = cnt;
  __syncthreads();
  for (int s = 1; s < 256; s <<= 1) {
    int u = (tid >= s) ? scan[tid - s] : 0;
    __syncthreads();
    scan[tid] += u;
    __syncthreads();
  }
  int pos = scan[tid] - cnt;
  int total = scan[255];
  int cntPad = (total + 63) & ~63;
  if (cntPad > KCAP) cntPad = KCAP;
  unsigned char bs[16];
  *(uint4*)bs = v;
#pragma unroll
  for (int i = 0; i < 16; ++i) {
    int c = tid * 16 + i;
    if (bs[i]) {
      if (pos < KCAP) {
        gidx[t * KCAP + pos] = (unsigned short)c;
        ppos[(size_t)t * CIN + c] = (unsigned short)pos;
      } else {
        ppos[(size_t)t * CIN + c] = 0xFFFF;
      }
      ++pos;
    } else {
      ppos[(size_t)t * CIN + c] = 0xFFFF;
    }
  }
  for (int k = total + tid; k < cntPad; k += 256) gidx[t * KCAP + k] = 0;
  if (tid == 0) { cnts[t] = cntPad; tots[t] = total; }
}

// ---------------------------------------------------------------------------
// P3: compacted fp16 hi/lo planes. Coalesced x reads, scattered u16 writes.
// Grid (TILES*8): block = (tile, 8 rows).
// ---------------------------------------------------------------------------
__global__ __launch_bounds__(256) void k_compact(const float* __restrict__ x,
                                                 const unsigned short* __restrict__ ppos,
                                                 const int* __restrict__ cnts,
                                                 const int* __restrict__ tots,
                                                 unsigned short* __restrict__ xch,
                                                 unsigned short* __restrict__ xcl) {
  int t = blockIdx.x >> 3;
  int rg = blockIdx.x & 7;
  int tid = threadIdx.x;
  int cntPad = cnts[t];
  int total = tots[t];
  const unsigned short* pp = ppos + (size_t)t * CIN;
  for (int r = rg * 8; r < rg * 8 + 8; ++r) {
    int row = t * 64 + r;
    const float4* xr = (const float4*)(x + (size_t)row * CIN);
    size_t ob = (size_t)row * KCAP;
    for (int k = total + tid; k < cntPad; k += 256) { xch[ob + k] = 0; xcl[ob + k] = 0; }
    for (int j = tid; j < CIN / 4; j += 256) {
      float4 v = xr[j];
      ushort4 p = *(const ushort4*)(pp + j * 4);
      float vv[4] = {v.x, v.y, v.z, v.w};
      unsigned short ps[4] = {p.x, p.y, p.z, p.w};
#pragma unroll
      for (int e = 0; e < 4; ++e) {
        if (ps[e] != 0xFFFF) {
          _Float16 h = (_Float16)vv[e];
          _Float16 l = (_Float16)(vv[e] - (float)h);
          xch[ob + ps[e]] = f16b(h);
          xcl[ob + ps[e]] = f16b(l);
        }
      }
    }
  }
}

// ---------------------------------------------------------------------------
// Kernel 3: sparse GEMM, 64x256 tile, 4 waves. Double-buffered A staging with
// one barrier per K-step: stage(next) issued at iter start, vmcnt(0)+s_barrier
// at iter end (stage latency hides under compute). B gathered global->VGPR,
// unpacked with v_perm. 3-term fp16 split MFMA.
// ---------------------------------------------------------------------------
__global__ __launch_bounds__(256, 2) void k_gemm(const uint32_t* __restrict__ Wtp,
                                                 const unsigned short* __restrict__ gidx,
                                                 const int* __restrict__ cnts,
                                                 const unsigned short* __restrict__ xch,
                                                 const unsigned short* __restrict__ xcl,
                                                 const float* __restrict__ bias,
                                                 float* __restrict__ out) {
  __shared__ __attribute__((aligned(16))) char sA[2][16384];  // per buf: [0,8K) hi, [8K,16K) lo

  int bid = blockIdx.x + gridDim.x * blockIdx.y;
  int xcd = bid & 7;
  int i = bid >> 3;            // 0..511
  int t = i & 255;
  int o0 = ((xcd << 1) + (i >> 8)) << 8;   // per-XCD 1MB Wtp col-stripe, 256 blocks deep

  int tid = threadIdx.x;
  int lane = tid & 63;
  int w = tid >> 6;
  int l15 = lane & 15, g = lane >> 4;
  int cntPad = cnts[t];
  int nt = cntPad >> 6;

  floatx4 acc[4][4];
#pragma unroll
  for (int m = 0; m < 4; ++m)
#pragma unroll
    for (int n = 0; n < 4; ++n) acc[m][n] = (floatx4)0.f;

  // staging source pre-unswizzle (content lands XOR-swizzled in LDS)
  int jx = ((lane & 7) * 16) ^ (((lane >> 3) & 7) << 4);
  int brow_s = lane >> 3;
  const int tKC = t * KCAP;

  auto STAGE = [&](int buf, int kk) {
#pragma unroll
    for (int q = 0; q < 4; ++q) {
      int ch = w + 4 * q;              // 16 1KB chunks over 2 planes
      int plane = ch >> 3;
      int coff = (ch & 7) * 1024;
      int b = ((ch & 7) << 3) + brow_s;
      const unsigned short* srcp = plane ? xcl : xch;
      const char* gsrc = (const char*)(srcp + ((size_t)(t * 64 + b) * KCAP + kk)) + jx;
      gl_lds16(gsrc, &sA[buf][plane * 8192 + coff]);
    }
  };

  if (nt > 0) STAGE(0, 0);
  asm volatile("s_waitcnt vmcnt(0)" ::: "memory");
  __builtin_amdgcn_s_barrier();

  for (int it = 0; it < nt; ++it) {
    int cur = it & 1;
    int k0 = it << 6;

    // index loads FIRST (so consuming them doesn't force the stage loads)
    int cI[2][8];
#pragma unroll
    for (int ks = 0; ks < 2; ++ks)
#pragma unroll
      for (int q = 0; q < 8; ++q)
        cI[ks][q] = gidx[tKC + k0 + ks * 32 + g * 8 + q];

    // issue next-tile staging; completes under this iteration's compute
    if (it + 1 < nt) STAGE(cur ^ 1, k0 + 64);

    const char* sbase = sA[cur];
#pragma unroll
    for (int ks = 0; ks < 2; ++ks) {
      f16x8 Ah[4], Al[4];
#pragma unroll
      for (int m = 0; m < 4; ++m) {
        int b = m * 16 + l15;
        int off = (b * 128 + ks * 64 + g * 16) ^ ((b & 7) << 4);
        Ah[m] = *(const f16x8*)(sbase + off);
        Al[m] = *(const f16x8*)(sbase + 8192 + off);
      }
#pragma unroll
      for (int n = 0; n < 4; ++n) {
        int ocol = o0 + w * 64 + n * 16 + l15;
        uint32_t wv[8];
#pragma unroll
        for (int q = 0; q < 8; ++q)
          wv[q] = Wtp[((unsigned)cI[ks][q] << 12) + (unsigned)ocol];
        union { f16x8 v; uint32_t u[4]; } Bh, Bl;
#pragma unroll
        for (int j = 0; j < 4; ++j) {
          Bh.u[j] = __builtin_amdgcn_perm(wv[2 * j + 1], wv[2 * j], 0x07060302u);
          Bl.u[j] = __builtin_amdgcn_perm(wv[2 * j + 1], wv[2 * j], 0x05040100u);
        }
        __builtin_amdgcn_s_setprio(1);
#pragma unroll
        for (int m = 0; m < 4; ++m) {
          acc[m][n] = __builtin_amdgcn_mfma_f32_16x16x32_f16(Ah[m], Bh.v, acc[m][n], 0, 0, 0);
          acc[m][n] = __builtin_amdgcn_mfma_f32_16x16x32_f16(Al[m], Bh.v, acc[m][n], 0, 0, 0);
          acc[m][n] = __builtin_amdgcn_mfma_f32_16x16x32_f16(Ah[m], Bl.v, acc[m][n], 0, 0, 0);
        }
        __builtin_amdgcn_s_setprio(0);
      }
    }

    // one barrier per K-step: all stage writes landed + all waves done reading
    asm volatile("s_waitcnt vmcnt(0)" ::: "memory");
    __builtin_amdgcn_s_barrier();
  }

  // epilogue: D row = (lane>>4)*4 + r, col = lane&15
#pragma unroll
  for (int n = 0; n < 4; ++n) {
    int ocol = o0 + w * 64 + n * 16 + l15;
    float bv = bias[ocol];
#pragma unroll
    for (int m = 0; m < 4; ++m) {
      int row0 = t * 64 + m * 16 + g * 4;
#pragma unroll
      for (int r = 0; r < 4; ++r)
        out[(size_t)(row0 + r) * COUT + ocol] = acc[m][n][r] + bv;
    }
  }
}

// ---------------------------------------------------------------------------
// Fallback: plain dense fp32 tiled GEMM (only if ws_size too small).
// ---------------------------------------------------------------------------
__global__ __launch_bounds__(256) void k_dense_fallback(const float* __restrict__ x,
                                                        const float* __restrict__ W,
                                                        const float* __restrict__ bias,
                                                        float* __restrict__ out) {
  __shared__ float As[64][17];
  __shared__ float Bs[16][65];
  int r0 = blockIdx.y << 6, c0 = blockIdx.x << 6;
  int tid = threadIdx.x;
  int ty = tid >> 4, tx = tid & 15;
  float acc[4][4] = {};
  for (int k0 = 0; k0 < CIN; k0 += 16) {
    __syncthreads();
    {
      int bb = tid >> 2, kk = (tid & 3) * 4;
      float4 va = *(const float4*)&x[(size_t)(r0 + bb) * CIN + k0 + kk];
      As[bb][kk] = va.x; As[bb][kk + 1] = va.y; As[bb][kk + 2] = va.z; As[bb][kk + 3] = va.w;
      float4 vb = *(const float4*)&W[(size_t)(c0 + bb) * CIN + k0 + kk];
      Bs[kk][bb] = vb.x; Bs[kk + 1][bb] = vb.y; Bs[kk + 2][bb] = vb.z; Bs[kk + 3][bb] = vb.w;
    }
    __syncthreads();
#pragma unroll
    for (int kk = 0; kk < 16; ++kk) {
      float a[4], b[4];
#pragma unroll
      for (int q = 0; q < 4; ++q) a[q] = As[ty * 4 + q][kk];
#pragma unroll
      for (int j = 0; j < 4; ++j) b[j] = Bs[kk][tx * 4 + j];
#pragma unroll
      for (int q = 0; q < 4; ++q)
#pragma unroll
        for (int j = 0; j < 4; ++j) acc[q][j] += a[q] * b[j];
    }
  }
#pragma unroll
  for (int q = 0; q < 4; ++q) {
    int row = r0 + ty * 4 + q;
#pragma unroll
    for (int j = 0; j < 4; ++j) {
      int col = c0 + tx * 4 + j;
      out[(size_t)row * COUT + col] = acc[q][j] + bias[col];
    }
  }
}

extern "C" void kernel_launch(void* const* d_in, const int* in_sizes, int n_in,
                              void* d_out, int out_size, void* d_ws, size_t ws_size,
                              hipStream_t stream) {
  (void)in_sizes; (void)n_in; (void)out_size;
  const float* x = (const float*)d_in[0];
  const float* W = (const float*)d_in[1];
  const float* bias = (const float*)d_in[2];
  float* out = (float*)d_out;

  size_t offWtp = 0;
  size_t offXch = offWtp + (size_t)CIN * COUT * 4;       // 64 MB
  size_t offXcl = offXch + (size_t)N_ROWS * KCAP * 2;    // +64 MB
  size_t offIdx = offXcl + (size_t)N_ROWS * KCAP * 2;    // +64 MB
  size_t offPpos = offIdx + (size_t)TILES * KCAP * 2;    // +1 MB
  size_t offFlag = offPpos + (size_t)TILES * CIN * 2;    // +2 MB
  size_t offCnt = offFlag + (size_t)TILES * CIN;         // +1 MB
  size_t offTot = offCnt + 4096;
  size_t need = offTot + 4096;

  if (ws_size < need) {
    dim3 g(COUT / 64, N_ROWS / 64);
    k_dense_fallback<<<g, 256, 0, stream>>>(x, W, bias, out);
    return;
  }

  char* ws = (char*)d_ws;
  uint32_t* Wtp = (uint32_t*)(ws + offWtp);
  unsigned short* xch = (unsigned short*)(ws + offXch);
  unsigned short* xcl = (unsigned short*)(ws + offXcl);
  unsigned short* gidx = (unsigned short*)(ws + offIdx);
  unsigned short* ppos = (unsigned short*)(ws + offPpos);
  unsigned char* flags = (unsigned char*)(ws + offFlag);
  int* cnts = (int*)(ws + offCnt);
  int* tots = (int*)(ws + offTot);

  k_wsplit<<<dim3(64 * 64), 256, 0, stream>>>(W, Wtp);
  k_colmax<<<dim3(TILES * 4), 256, 0, stream>>>(x, flags);
  k_scan<<<dim3(TILES), 256, 0, stream>>>(flags, gidx, cnts, tots, ppos);
  k_compact<<<dim3(TILES * 8), 256, 0, stream>>>(x, ppos, cnts, tots, xch, xcl);
  k_gemm<<<dim3(COUT / 256, TILES), 256, 0, stream>>>(Wtp, gidx, cnts, xch, xcl, bias, out);
}